// Round 3
// baseline (53.105 us; speedup 1.0000x reference)
//
#include <hip/hip_runtime.h>
#include <hip/hip_bf16.h>

// Problem constants
constexpr int B = 48, J = 17, H = 128, W = 128, P = 30;
constexpr int HW = H * W;            // 16384
constexpr int NPLANES = B * J;       // 816
constexpr int AE_BLOCKS = B;         // 48
// ws layout (16 bytes, zeroed by memset node each replay):
//   [0:8)   u64 fixed-point sum of masked per-plane mse  (scale 2^32)
//   [8:12)  u32 mask count
//   [12:16) u32 done-ticket counter

__global__ __launch_bounds__(256) void fused_kernel(
        const float* __restrict__ outputs,
        const float* __restrict__ heatmaps,
        const unsigned* __restrict__ joints_u32,
        unsigned long long* __restrict__ ws64,
        float* __restrict__ out) {
    int t = threadIdx.x;

    if (blockIdx.x >= AE_BLOCKS) {
        // ---- MSE: one full plane per block ----
        int plane = blockIdx.x - AE_BLOCKS;         // 0..815
        int b = plane / J, j = plane % J;
        const float4* pred = reinterpret_cast<const float4*>(
            outputs + ((size_t)b * 2 * J + j) * HW);
        const float4* gt = reinterpret_cast<const float4*>(
            heatmaps + (size_t)plane * HW);

        float sq = 0.f, gs = 0.f;
#pragma unroll
        for (int k = 0; k < 16; ++k) {
            float4 p = pred[t + k * 256];
            float4 g = gt[t + k * 256];
            float d0 = p.x - g.x, d1 = p.y - g.y, d2 = p.z - g.z, d3 = p.w - g.w;
            sq += d0 * d0 + d1 * d1 + d2 * d2 + d3 * d3;
            gs += g.x + g.y + g.z + g.w;
        }
        for (int off = 32; off > 0; off >>= 1) {
            sq += __shfl_xor(sq, off);
            gs += __shfl_xor(gs, off);
        }
        __shared__ float s_sq[4], s_gs[4];
        int wave = t >> 6;
        if ((t & 63) == 0) { s_sq[wave] = sq; s_gs[wave] = gs; }
        __syncthreads();
        if (t == 0) {
            float tot_sq = s_sq[0] + s_sq[1] + s_sq[2] + s_sq[3];
            float tot_gs = s_gs[0] + s_gs[1] + s_gs[2] + s_gs[3];
            unsigned* ws32 = reinterpret_cast<unsigned*>(ws64);
            if (tot_gs > 0.f) {
                // mse*2^32 = tot_sq * 2^32 / 16384 = tot_sq * 2^18 (exact-ish, deterministic)
                unsigned long long fx = (unsigned long long)
                    __double2ll_rn((double)tot_sq * 262144.0);
                atomicAdd(ws64, fx);
                atomicAdd(ws32 + 2, 1u);
            }
            __threadfence();
            unsigned ticket = atomicAdd(ws32 + 3, 1u);
            if (ticket == NPLANES - 1) {
                __threadfence();
                unsigned long long acc = atomicAdd(ws64, 0ull);
                unsigned cnt = atomicAdd(ws32 + 2, 0u);
                out[0] = (float)((double)acc * (1.0 / 4294967296.0) / (double)cnt);
            }
        }
        return;
    }

    // ---- AE for batch b (blocks 0..47) ----
    int b = blockIdx.x;
    const float* tags = outputs + ((size_t)b * 2 * J + J) * HW;

    // dtype probe on this batch's joints region (int64-assumed layout):
    // P*J*2 = 1020 int64 values -> odd u32 words all zero iff int64.
    const unsigned* jw = joints_u32 + (size_t)b * P * J * 2 * 2;
    unsigned ob = 0;
#pragma unroll
    for (int k = 0; k < 4; ++k) {
        int i = t + k * 256;
        if (i < P * J * 2) ob |= jw[2 * i + 1];
    }
    __shared__ unsigned s_ob[4];
    for (int off = 32; off > 0; off >>= 1) ob |= (unsigned)__shfl_xor((int)ob, off);
    int wv = t >> 6;
    if ((t & 63) == 0) s_ob[wv] = ob;
    __shared__ float m_sh[P];
    __shared__ int v_sh[P];
    __syncthreads();
    bool is64 = (s_ob[0] | s_ob[1] | s_ob[2] | s_ob[3]) == 0u;

    if (t >= 64) return;
    int lane = t;

    float per_pull = 0.f, m = 0.f;
    int validp = 0;

    if (lane < P) {
        float tv[J];
        int   vv[J];
        int cnt = 0;
        float sum = 0.f;
        if (is64) {
            const long long* jp = reinterpret_cast<const long long*>(joints_u32)
                                  + ((size_t)b * P + lane) * J * 2;
#pragma unroll
            for (int j = 0; j < J; ++j) {
                int idx = (int)jp[2 * j];
                int vis = jp[2 * j + 1] > 0;
                float tval = tags[idx];
                tv[j] = tval; vv[j] = vis;
                cnt += vis;
                sum += vis ? tval : 0.f;
            }
        } else {
            const int* jp = reinterpret_cast<const int*>(joints_u32)
                            + ((size_t)b * P + lane) * J * 2;
#pragma unroll
            for (int j = 0; j < J; ++j) {
                int idx = jp[2 * j];
                int vis = jp[2 * j + 1] > 0;
                float tval = tags[idx];
                tv[j] = tval; vv[j] = vis;
                cnt += vis;
                sum += vis ? tval : 0.f;
            }
        }
        float safe = cnt > 0 ? (float)cnt : 1.f;
        m = sum / safe;
        float pp = 0.f;
#pragma unroll
        for (int j = 0; j < J; ++j) {
            float d = tv[j] - m;
            pp += vv[j] ? d * d : 0.f;
        }
        validp = (cnt > 0) ? 1 : 0;
        per_pull = validp ? pp / safe : 0.f;
        m_sh[lane] = m;
        v_sh[lane] = validp;
    }
    // single wave: drain LDS writes so all lanes see m_sh/v_sh
    __builtin_amdgcn_s_waitcnt(0);

    float push_p = 0.f;
    if (lane < P && validp) {
#pragma unroll
        for (int k = 0; k < P; ++k) {
            if (v_sh[k]) {
                float d = m - m_sh[k];
                push_p += __expf(-d * d);
            }
        }
    }

    float v0 = per_pull, v1 = push_p, v2 = (float)validp;
    for (int off = 32; off > 0; off >>= 1) {
        v0 += __shfl_xor(v0, off);
        v1 += __shfl_xor(v1, off);
        v2 += __shfl_xor(v2, off);
    }
    if (lane == 0) {
        float num_tags = v2;
        float pull = v0 / fmaxf(num_tags, 1.f);
        float push_raw = v1 - num_tags;
        float denom = (num_tags - 1.f) * num_tags;
        float push = (num_tags >= 2.f) ? (push_raw / (denom > 0.f ? denom : 1.f)) * 0.5f : 0.f;
        out[1 + b] = push;
        out[1 + B + b] = pull;
    }
}

extern "C" void kernel_launch(void* const* d_in, const int* in_sizes, int n_in,
                              void* d_out, int out_size, void* d_ws, size_t ws_size,
                              hipStream_t stream) {
    const float* outputs  = (const float*)d_in[0];
    const float* heatmaps = (const float*)d_in[1];
    const unsigned* joints = (const unsigned*)d_in[2];
    float* out = (float*)d_out;

    hipMemsetAsync(d_ws, 0, 16, stream);   // zero acc/cnt/ticket each replay
    fused_kernel<<<AE_BLOCKS + NPLANES, 256, 0, stream>>>(
        outputs, heatmaps, joints,
        reinterpret_cast<unsigned long long*>(d_ws), out);
}

// Round 4
// 24.163 us; speedup vs baseline: 2.1978x; 2.1978x over previous
//
#include <hip/hip_runtime.h>
#include <hip/hip_bf16.h>

// Problem constants
constexpr int B = 48, J = 17, H = 128, W = 128, P = 30;
constexpr int HW = H * W;                   // 16384
constexpr int NPLANES = B * J;              // 816
constexpr int SUBS = 4;                     // chunks per plane
constexpr int CHUNK_FLOATS = HW / SUBS;     // 4096
constexpr int NCHUNK = NPLANES * SUBS;      // 3264
constexpr int AE_BLOCKS = B;                // 48
// ws layout: float2 ws2[NCHUNK], ws2[plane*SUBS+sub] = {sq_partial, gtsum_partial}

// ---------------- Kernel A: AE (blocks 0..47) + MSE chunks (blocks 48..3311) ----------------
__global__ __launch_bounds__(256) void fused_kernel(
        const float* __restrict__ outputs,
        const float* __restrict__ heatmaps,
        const unsigned* __restrict__ joints_u32,
        float2* __restrict__ ws2,
        float* __restrict__ out) {
    int t = threadIdx.x;

    if (blockIdx.x >= AE_BLOCKS) {
        // ---- MSE quarter-plane chunk ----
        int chunk = blockIdx.x - AE_BLOCKS;     // 0..3263
        int plane = chunk >> 2, sub = chunk & 3;
        int b = plane / J, j = plane % J;
        const float4* pred = reinterpret_cast<const float4*>(
            outputs + ((size_t)b * 2 * J + j) * HW + sub * CHUNK_FLOATS);
        const float4* gt = reinterpret_cast<const float4*>(
            heatmaps + (size_t)plane * HW + sub * CHUNK_FLOATS);

        float sq = 0.f, gs = 0.f;
#pragma unroll
        for (int k = 0; k < CHUNK_FLOATS / 4 / 256; ++k) {   // 4 iters
            float4 p = pred[t + k * 256];
            float4 g = gt[t + k * 256];
            float d0 = p.x - g.x, d1 = p.y - g.y, d2 = p.z - g.z, d3 = p.w - g.w;
            sq += d0 * d0 + d1 * d1 + d2 * d2 + d3 * d3;
            gs += g.x + g.y + g.z + g.w;
        }
        for (int off = 32; off > 0; off >>= 1) {
            sq += __shfl_xor(sq, off);
            gs += __shfl_xor(gs, off);
        }
        __shared__ float s_sq[4], s_gs[4];
        int wave = t >> 6;
        if ((t & 63) == 0) { s_sq[wave] = sq; s_gs[wave] = gs; }
        __syncthreads();
        if (t == 0) {
            ws2[chunk] = make_float2(s_sq[0] + s_sq[1] + s_sq[2] + s_sq[3],
                                     s_gs[0] + s_gs[1] + s_gs[2] + s_gs[3]);
        }
        return;
    }

    // ---- AE for batch b (blocks 0..47) ----
    int b = blockIdx.x;
    const float* tags = outputs + ((size_t)b * 2 * J + J) * HW;

    // dtype probe on this batch's joints region (int64-assumed layout):
    // P*J*2 = 1020 int64 values -> odd u32 words all zero iff int64.
    const unsigned* jw = joints_u32 + (size_t)b * P * J * 2 * 2;
    unsigned ob = 0;
#pragma unroll
    for (int k = 0; k < 4; ++k) {
        int i = t + k * 256;
        if (i < P * J * 2) ob |= jw[2 * i + 1];
    }
    __shared__ unsigned s_ob[4];
    for (int off = 32; off > 0; off >>= 1) ob |= (unsigned)__shfl_xor((int)ob, off);
    int wv = t >> 6;
    if ((t & 63) == 0) s_ob[wv] = ob;
    __shared__ float m_sh[P];
    __shared__ int v_sh[P];
    __syncthreads();
    bool is64 = (s_ob[0] | s_ob[1] | s_ob[2] | s_ob[3]) == 0u;

    if (t >= 64) return;
    int lane = t;

    float per_pull = 0.f, m = 0.f;
    int validp = 0;

    if (lane < P) {
        float tv[J];
        int   vv[J];
        int cnt = 0;
        float sum = 0.f;
        if (is64) {
            const long long* jp = reinterpret_cast<const long long*>(joints_u32)
                                  + ((size_t)b * P + lane) * J * 2;
#pragma unroll
            for (int j = 0; j < J; ++j) {
                int idx = (int)jp[2 * j];
                int vis = jp[2 * j + 1] > 0;
                float tval = tags[idx];
                tv[j] = tval; vv[j] = vis;
                cnt += vis;
                sum += vis ? tval : 0.f;
            }
        } else {
            const int* jp = reinterpret_cast<const int*>(joints_u32)
                            + ((size_t)b * P + lane) * J * 2;
#pragma unroll
            for (int j = 0; j < J; ++j) {
                int idx = jp[2 * j];
                int vis = jp[2 * j + 1] > 0;
                float tval = tags[idx];
                tv[j] = tval; vv[j] = vis;
                cnt += vis;
                sum += vis ? tval : 0.f;
            }
        }
        float safe = cnt > 0 ? (float)cnt : 1.f;
        m = sum / safe;
        float pp = 0.f;
#pragma unroll
        for (int j = 0; j < J; ++j) {
            float d = tv[j] - m;
            pp += vv[j] ? d * d : 0.f;
        }
        validp = (cnt > 0) ? 1 : 0;
        per_pull = validp ? pp / safe : 0.f;
        m_sh[lane] = m;
        v_sh[lane] = validp;
    }
    // single wave: drain LDS writes so all lanes see m_sh/v_sh
    __builtin_amdgcn_s_waitcnt(0);

    float push_p = 0.f;
    if (lane < P && validp) {
#pragma unroll
        for (int k = 0; k < P; ++k) {
            if (v_sh[k]) {
                float d = m - m_sh[k];
                push_p += __expf(-d * d);
            }
        }
    }

    float v0 = per_pull, v1 = push_p, v2 = (float)validp;
    for (int off = 32; off > 0; off >>= 1) {
        v0 += __shfl_xor(v0, off);
        v1 += __shfl_xor(v1, off);
        v2 += __shfl_xor(v2, off);
    }
    if (lane == 0) {
        float num_tags = v2;
        float pull = v0 / fmaxf(num_tags, 1.f);
        float push_raw = v1 - num_tags;
        float denom = (num_tags - 1.f) * num_tags;
        float push = (num_tags >= 2.f) ? (push_raw / (denom > 0.f ? denom : 1.f)) * 0.5f : 0.f;
        out[1 + b] = push;
        out[1 + B + b] = pull;
    }
}

// ---------------- Kernel B: fold per-chunk partials -> out[0] ----------------
__global__ __launch_bounds__(256) void finalize_kernel(const float2* __restrict__ ws2,
                                                       float* __restrict__ out) {
    int t = threadIdx.x;
    float s = 0.f, c = 0.f;
    for (int p = t; p < NPLANES; p += 256) {
        float sq = 0.f, gs = 0.f;
#pragma unroll
        for (int sub = 0; sub < SUBS; ++sub) {
            float2 v = ws2[p * SUBS + sub];
            sq += v.x; gs += v.y;
        }
        bool mask = gs > 0.f;
        s += mask ? sq * (1.f / HW) : 0.f;
        c += mask ? 1.f : 0.f;
    }
    for (int off = 32; off > 0; off >>= 1) {
        s += __shfl_xor(s, off);
        c += __shfl_xor(c, off);
    }
    __shared__ float s_s[4], s_c[4];
    int wave = t >> 6;
    if ((t & 63) == 0) { s_s[wave] = s; s_c[wave] = c; }
    __syncthreads();
    if (t == 0) {
        out[0] = (s_s[0] + s_s[1] + s_s[2] + s_s[3]) /
                 (s_c[0] + s_c[1] + s_c[2] + s_c[3]);
    }
}

extern "C" void kernel_launch(void* const* d_in, const int* in_sizes, int n_in,
                              void* d_out, int out_size, void* d_ws, size_t ws_size,
                              hipStream_t stream) {
    const float* outputs  = (const float*)d_in[0];
    const float* heatmaps = (const float*)d_in[1];
    const unsigned* joints = (const unsigned*)d_in[2];
    float* out = (float*)d_out;
    float2* ws2 = (float2*)d_ws;

    fused_kernel<<<AE_BLOCKS + NCHUNK, 256, 0, stream>>>(outputs, heatmaps, joints, ws2, out);
    finalize_kernel<<<1, 256, 0, stream>>>(ws2, out);
}